// Round 2
// baseline (302.114 us; speedup 1.0000x reference)
//
#include <hip/hip_runtime.h>
#include <cstdint>

// ShortTermLSTM on MI355X: batched LSTM, transposed-GEMM f16 MFMA, cell fully
// in registers, fused-rcp activations in the exp2 domain (raw v_exp_f32).
// R14 292: exp2-pre-scaled weights. R15 251 steady: k-col permutation +
// single barrier. R15 post-mortem: SQ_LDS_BANK_CONFLICT identical pre/post
// write-permutation -> counter tracks inherent b128 serialization, not
// aliasing. Occupancy model: reg quantum steps at 64/128/256 (m69) -> any
// (128,256] kernel = 2 waves/SIMD = 2 blocks/CU -> 768 blocks = 1.5 dispatch
// rounds (tail = 15-35% of wall). Registers are FREE up to 256.
// R16 (this): 256 blocks x 512 threads x 48 seqs (3 MFMA seq-groups), exactly
// 1 block/CU -> no tail, balanced; ALL W in regs (wfrag 4 tiles x 4 kc = 64,
// reused across the 3 groups); s_W deleted (-25 LDS b128 reads/step); LDS
// 26,112 B. Wave w: tiles {w,w+8,w+16} x groups 0..2 (9 docells); waves 0..2
// carry tile 24 for group=wavu (10th). One barrier/step.
//   k-map (unchanged from R15; prep mirrors it):
//     h unit u=(t,q), t<24 : k = 8*(t>>1) + (t&1) + 2q   (0..95)
//     h unit 96+q (t=24)   : k = 96 + 2q
//     x_hi*W_hi c          : k = 104 + 2c ; x_lo*W_hi c : k = 105 + 2c
//     x_hi*W_lo c          : k = 112 + 2c ; bias hi/lo  : k = 120 / 122
// Residual error: dropped h*W_hh_lo (~6e-5/step); measured margin ~4x.

#define H_UNITS 100
#define T_STEPS 128
#define SEQ_BLK 48
#define NSEQ    12288
#define NBLK    (NSEQ / SEQ_BLK)   // 256 = 1 block/CU
#define KSTR    136                // LDS h row stride (ushorts)
#define GRP     (16 * KSTR)        // ushorts per seq-group = 2176
#define BUFU    (3 * GRP)          // ushorts per ping-pong buffer = 6528
#define LOG2E   1.4426950408889634f
#define TWO_L   2.8853900817779268f   // 2*log2(e)

typedef __attribute__((ext_vector_type(8))) _Float16 halfx8;
typedef __attribute__((ext_vector_type(8))) unsigned short ushortx8;
typedef __attribute__((ext_vector_type(4))) float floatx4;

__device__ __forceinline__ unsigned short f32_to_f16u(float x) {
    _Float16 h = (_Float16)x;                       // v_cvt_f16_f32 (RNE)
    return __builtin_bit_cast(unsigned short, h);
}
__device__ __forceinline__ float f16u_to_f32(unsigned short u) {
    _Float16 h = __builtin_bit_cast(_Float16, u);
    return (float)h;
}
#if __has_builtin(__builtin_amdgcn_exp2f)
__device__ __forceinline__ float fexp2(float x) { return __builtin_amdgcn_exp2f(x); }
#else
__device__ __forceinline__ float fexp2(float x) { return exp2f(x); }
#endif

// ---------------------------------------------------------------------------
// Prep: pack W (pre-scaled into exp2 domain) into MFMA A-operand fragment
// order with gate-interleaved rows, using the PERMUTED k-map above:
//   frag elem (tile,kc,lane,j) = Wsc[row n][orig(k)],  k = kc*32 + quad*8 + j.
// ---------------------------------------------------------------------------
__global__ void lstm_prep_pack(const float* __restrict__ W_ih,
                               const float* __restrict__ W_hh,
                               const float* __restrict__ b_ih,
                               const float* __restrict__ b_hh,
                               ushortx8* __restrict__ Bpack) {
    int t = blockIdx.x * 256 + threadIdx.x;   // (tile,kc,lane) flattened: 25*4*64 = 6400
    if (t >= 25 * 4 * 64) return;
    int lane = t & 63;
    int kc   = (t >> 6) & 3;
    int tile = t >> 8;
    int m    = lane & 15;
    int n  = (m & 3) * 100 + tile * 4 + (m >> 2);   // permuted gate row (i,f,g,o = m&3)
    float sc = (n >= 200 && n < 300) ? (2.0f * LOG2E) : LOG2E;   // g rows get 2x
    int k0 = kc * 32 + ((lane >> 4) & 3) * 8;
    ushortx8 v;
#pragma unroll
    for (int j = 0; j < 8; ++j) {
        int k = k0 + j;
        unsigned short w = 0;
        if (k < 96) {
            // inverse of k = 8*(t>>1)+(t&1)+2q
            int u = ((k >> 3) << 3) + ((k & 1) << 2) + ((k & 7) >> 1);
            w = f32_to_f16u(W_hh[n * 100 + u] * sc);
        } else if (k < 104) {
            if (!(k & 1)) {                       // k 96,98,100,102: units 96..99
                int u = 96 + ((k - 96) >> 1);
                w = f32_to_f16u(W_hh[n * 100 + u] * sc);
            }
        } else if (k < 112) {
            // even k=104+2c: x_hi * W_hi ; odd k=105+2c: x_lo * W_hi
            int c = (k - 104) >> 1;
            w = f32_to_f16u(W_ih[n * 4 + c] * sc);
        } else if (k < 120) {
            if (!(k & 1)) {                       // k=112+2c: x_hi * W_lo
                int c = (k - 112) >> 1;
                float wf = W_ih[n * 4 + c] * sc;
                unsigned short hi = f32_to_f16u(wf);
                w = f32_to_f16u(wf - f16u_to_f32(hi));
            }
        } else if (k == 120) {                    // b_hi (scaled), A = 1.0
            float bb = (b_ih[n] + b_hh[n]) * sc;
            w = f32_to_f16u(bb);
        } else if (k == 122) {                    // b_lo (scaled), A = 1.0
            float bb = (b_ih[n] + b_hh[n]) * sc;
            unsigned short hi = f32_to_f16u(bb);
            w = f32_to_f16u(bb - f16u_to_f32(hi));
        }
        v[j] = w;
    }
    Bpack[t] = v;
}

// ---------------------------------------------------------------------------
// Main: one block = 48 sequences (3 MFMA groups), 8 waves, full T loop.
// ---------------------------------------------------------------------------
__global__ void __launch_bounds__(512, 2)
lstm_main(const float* __restrict__ x, const ushortx8* __restrict__ Bpack,
          float* __restrict__ out) {
    __shared__ __align__(16) unsigned short s_A[2 * BUFU];   // 26,112 B total

    const int tid  = threadIdx.x;
    const int lane = tid & 63;
    const int wavu = __builtin_amdgcn_readfirstlane(tid >> 6);   // 0..7
    const int seq0 = blockIdx.x * SEQ_BLK;
    const int m    = lane & 15;
    const int quad = lane >> 4;
    const int q2   = quad << 1;

    // ---- W fragments: ALL kc in regs. Slots 0..2 = tiles {wavu, wavu+8,
    // wavu+16}; slot 3 = tile 24 (waves 0..2 only). 64 regs, reused x3 groups.
    halfx8 wfrag[4][4];
#pragma unroll
    for (int it = 0; it < 3; ++it) {
        int tile = wavu + it * 8;
#pragma unroll
        for (int kc = 0; kc < 4; ++kc)
            wfrag[it][kc] = __builtin_bit_cast(halfx8, Bpack[(tile * 4 + kc) * 64 + lane]);
    }
    if (wavu < 3) {
#pragma unroll
        for (int kc = 0; kc < 4; ++kc)
            wfrag[3][kc] = __builtin_bit_cast(halfx8, Bpack[(24 * 4 + kc) * 64 + lane]);
    }

    // h write-col base per slot tile (wave-uniform -> SGPR)
    int wb[3];
#pragma unroll
    for (int it = 0; it < 3; ++it) {
        int tile = wavu + it * 8;
        wb[it] = ((tile >> 1) << 3) + (tile & 1);
    }

    // refresh mapping (tid >= 128): 384 threads = 48 seqs x 8 refresh cols
    const int rt   = tid - 128;
    const int rtc  = rt < 0 ? 0 : rt;
    const int rs   = rtc >> 3;          // 0..47
    const int rc   = rtc & 7;
    const int roff = (rs >> 4) * GRP + (rs & 15) * KSTR;
    const float* xb = x + (size_t)(seq0 + rs) * (T_STEPS * 4) + (rc & 3);

    // ---- zero both buffers (h(0)=0; unused k columns stay 0 forever)
    for (int i = tid; i < BUFU; i += 512)        // 2*BUFU ushorts = BUFU u32
        ((unsigned int*)s_A)[i] = 0u;
    float x0 = 0.0f;
    if (tid >= 128) x0 = xb[0];
    __syncthreads();
    // ---- x(t=0) into buf0; constant bias cols into BOTH buffers
    if (tid >= 128) {
        unsigned short hi = f32_to_f16u(x0);
        if (rc < 4) {
            s_A[roff + 104 + 2 * rc] = hi;                         // x_hi (W_hi)
            s_A[roff + 112 + 2 * rc] = hi;                         // x_hi (W_lo)
        } else {
            s_A[roff + 105 + 2 * (rc - 4)] =
                f32_to_f16u(x0 - f16u_to_f32(hi));                 // x_lo (W_hi)
        }
    } else if (tid < 96) {
        // 96 rows = 2 bufs x 3 groups x 16 seqs; each writes both bias cols
        int b = tid / 48, r = tid % 48, g = r / 16, s = r & 15;
        s_A[b * BUFU + g * GRP + s * KSTR + 120] = 0x3C00;         // b_hi sel = 1.0
        s_A[b * BUFU + g * GRP + s * KSTR + 122] = 0x3C00;         // b_lo sel = 1.0
    }
    __syncthreads();

    float c9[3][3];   // cell state [slot][group], 2*log2e domain
#pragma unroll
    for (int it = 0; it < 3; ++it)
#pragma unroll
        for (int g = 0; g < 3; ++g) c9[it][g] = 0.0f;
    float c24 = 0.0f;

    const int aRow = m * KSTR + quad * 8;   // ushort idx within a group

    for (int t = 0; t < T_STEPS; ++t) {
        const int bR = t & 1;
        const unsigned short* baseR = s_A + bR * BUFU;
        unsigned short*       baseW = s_A + (bR ^ 1) * BUFU;

        // prefetch x(t+1) before compute phase
        float xnext = 0.0f;
        if (tid >= 128) {
            int tn = t + 1; if (tn > T_STEPS - 1) tn = T_STEPS - 1;
            xnext = xb[tn * 4];
        }

        // h/x fragments for all 3 seq-groups (one addr reg + imm offsets)
        halfx8 hh[3][4];
#pragma unroll
        for (int g = 0; g < 3; ++g)
#pragma unroll
            for (int kc = 0; kc < 4; ++kc)
                hh[g][kc] = *(const halfx8*)(baseR + g * GRP + aRow + kc * 32);

        const bool last = (t == T_STEPS - 1);

        auto docell = [&](const halfx8* w, const halfx8* hhg, float& cm,
                          int wbase, int jb, int g) {
            floatx4 acc = {0.0f, 0.0f, 0.0f, 0.0f};
            acc = __builtin_amdgcn_mfma_f32_16x16x32_f16(w[0], hhg[0], acc, 0, 0, 0);
            acc = __builtin_amdgcn_mfma_f32_16x16x32_f16(w[1], hhg[1], acc, 0, 0, 0);
            acc = __builtin_amdgcn_mfma_f32_16x16x32_f16(w[2], hhg[2], acc, 0, 0, 0);
            acc = __builtin_amdgcn_mfma_f32_16x16x32_f16(w[3], hhg[3], acc, 0, 0, 0);
            // lane = (seq m of group g, unit jb+quad); acc = {i,f,g,o}, exp2 dom
            float ei = fexp2(acc[0]);            // e^i
            float ef = fexp2(acc[1]);            // e^f
            float eg = fexp2(acc[2]);            // e^{2g}
            float eo = fexp2(acc[3]);            // e^o
            float a  = 1.0f + ei, b = 1.0f + ef;
            float d  = eg + 1.0f;
            float e2s = fmaf(eg, TWO_L, -TWO_L); // (e^{2g}-1)*2log2e
            float q  = a * d;
            float r  = __builtin_amdgcn_rcpf(q * b);
            float nm = fmaf(ef * q, cm, (ei * b) * e2s);
            float c2 = nm * r;
            cm = c2;
            float cc = fminf(c2, 115.0f);        // exp2 overflow guard
            float ec = fexp2(cc);                // e^{2c}
            float r2 = __builtin_amdgcn_rcpf((1.0f + eo) * (ec + 1.0f));
            float h  = (eo * (ec - 1.0f)) * r2;
            if (!last) {
                baseW[g * GRP + m * KSTR + wbase + q2] = f32_to_f16u(h);
            } else {
                out[(size_t)(seq0 + g * 16 + m) * H_UNITS + jb + quad] = h;
            }
        };

#pragma unroll
        for (int it = 0; it < 3; ++it)
#pragma unroll
            for (int g = 0; g < 3; ++g)
                docell(wfrag[it], hh[g], c9[it][g], wb[it], (wavu + it * 8) * 4, g);

        // tile 24 (units 96..99): waves 0..2, one group each (static hh index)
        if (wavu == 0)      docell(wfrag[3], hh[0], c24, 96, 96, 0);
        else if (wavu == 1) docell(wfrag[3], hh[1], c24, 96, 96, 1);
        else if (wavu == 2) docell(wfrag[3], hh[2], c24, 96, 96, 2);

        if (tid >= 128 && !last) {               // x(t+1) -> other buffer
            unsigned short hi = f32_to_f16u(xnext);
            if (rc < 4) {
                baseW[roff + 104 + 2 * rc] = hi;
                baseW[roff + 112 + 2 * rc] = hi;
            } else {
                baseW[roff + 105 + 2 * (rc - 4)] =
                    f32_to_f16u(xnext - f16u_to_f32(hi));
            }
        }
        __syncthreads();   // single barrier/step: covers both cross-step hazards
    }
}

extern "C" void kernel_launch(void* const* d_in, const int* in_sizes, int n_in,
                              void* d_out, int out_size, void* d_ws, size_t ws_size,
                              hipStream_t stream) {
    const float* x    = (const float*)d_in[0];   // [4096,3,128,4]
    const float* W_ih = (const float*)d_in[1];   // [400,4]
    const float* W_hh = (const float*)d_in[2];   // [400,100]
    const float* b_ih = (const float*)d_in[3];   // [400]
    const float* b_hh = (const float*)d_in[4];   // [400]
    ushortx8* Bpack = (ushortx8*)d_ws;           // 25*4*64*16 B = 102,400 B

    lstm_prep_pack<<<25, 256, 0, stream>>>(W_ih, W_hh, b_ih, b_hh, Bpack);
    lstm_main<<<NBLK, 512, 0, stream>>>(x, Bpack, (float*)d_out);
}

// Round 3
// 295.629 us; speedup vs baseline: 1.0219x; 1.0219x over previous
//
#include <hip/hip_runtime.h>
#include <cstdint>

// ShortTermLSTM on MI355X: batched LSTM, transposed-GEMM f16 MFMA, cell fully
// in registers, fused-rcp activations in the exp2 domain (raw v_exp_f32).
// R15 251 steady: k-col permutation + single barrier (768 x 4-wave blocks).
// R16 269 REGRESSED: mono-block 512-thread (balanced, no tail) — proves the
// 2-blocks/CU overlap across barriers is worth more than the 1.5-round tail.
// Occupancy model: unified-file granule 64 -> any (128,256] kernel = 2
// waves/SIMD; registers are FREE up to 256 total. R15 used only ~160.
// R17 (this): R15 geometry + register-fat two-phase schedule:
//   - ALL W kc0..3 in regs (wfrag[7][4] = 112 AGPR); s_W deleted; LDS 8704 B;
//     LDS b128 reads/wave/step 11 -> 4.
//   - per step: batch hh reads -> 7 independent MFMA 4-chains into acc[] ->
//     7 independent activation chains (7-way ILP for the exp/rcp chains).
//   k-map (prep mirrors it):
//     h unit u=(t,q), t<24 : k = 8*(t>>1) + (t&1) + 2q   (0..95)
//     h unit 96+q (t=24)   : k = 96 + 2q
//     x_hi*W_hi c          : k = 104 + 2c ; x_lo*W_hi c : k = 105 + 2c
//     x_hi*W_lo c          : k = 112 + 2c ; bias hi/lo  : k = 120 / 122
// Residual error: dropped h*W_hh_lo (~6e-5/step); measured margin ~4x.

#define H_UNITS 100
#define T_STEPS 128
#define S_BLK   16
#define NSEQ    12288
#define NBLK    (NSEQ / S_BLK)   // 768
#define NTILE   25               // 100 units / 4 per tile
#define KSTR    136              // LDS h row stride (ushorts)
#define LOG2E   1.4426950408889634f
#define TWO_L   2.8853900817779268f   // 2*log2(e)

typedef __attribute__((ext_vector_type(8))) _Float16 halfx8;
typedef __attribute__((ext_vector_type(8))) unsigned short ushortx8;
typedef __attribute__((ext_vector_type(4))) float floatx4;

__device__ __forceinline__ unsigned short f32_to_f16u(float x) {
    _Float16 h = (_Float16)x;                       // v_cvt_f16_f32 (RNE)
    return __builtin_bit_cast(unsigned short, h);
}
__device__ __forceinline__ float f16u_to_f32(unsigned short u) {
    _Float16 h = __builtin_bit_cast(_Float16, u);
    return (float)h;
}
#if __has_builtin(__builtin_amdgcn_exp2f)
__device__ __forceinline__ float fexp2(float x) { return __builtin_amdgcn_exp2f(x); }
#else
__device__ __forceinline__ float fexp2(float x) { return exp2f(x); }
#endif

// ---------------------------------------------------------------------------
// Prep: pack W (pre-scaled into exp2 domain) into MFMA A-operand fragment
// order with gate-interleaved rows, using the PERMUTED k-map above:
//   frag elem (tile,kc,lane,j) = Wsc[row n][orig(k)],  k = kc*32 + quad*8 + j.
// ---------------------------------------------------------------------------
__global__ void lstm_prep_pack(const float* __restrict__ W_ih,
                               const float* __restrict__ W_hh,
                               const float* __restrict__ b_ih,
                               const float* __restrict__ b_hh,
                               ushortx8* __restrict__ Bpack) {
    int t = blockIdx.x * 256 + threadIdx.x;   // (tile,kc,lane) flattened: 25*4*64 = 6400
    if (t >= NTILE * 4 * 64) return;
    int lane = t & 63;
    int kc   = (t >> 6) & 3;
    int tile = t >> 8;
    int m    = lane & 15;
    int n  = (m & 3) * 100 + tile * 4 + (m >> 2);   // permuted gate row (i,f,g,o = m&3)
    float sc = (n >= 200 && n < 300) ? (2.0f * LOG2E) : LOG2E;   // g rows get 2x
    int k0 = kc * 32 + ((lane >> 4) & 3) * 8;
    ushortx8 v;
#pragma unroll
    for (int j = 0; j < 8; ++j) {
        int k = k0 + j;
        unsigned short w = 0;
        if (k < 96) {
            // inverse of k = 8*(t>>1)+(t&1)+2q
            int u = ((k >> 3) << 3) + ((k & 1) << 2) + ((k & 7) >> 1);
            w = f32_to_f16u(W_hh[n * 100 + u] * sc);
        } else if (k < 104) {
            if (!(k & 1)) {                       // k 96,98,100,102: units 96..99
                int u = 96 + ((k - 96) >> 1);
                w = f32_to_f16u(W_hh[n * 100 + u] * sc);
            }
        } else if (k < 112) {
            // even k=104+2c: x_hi * W_hi ; odd k=105+2c: x_lo * W_hi
            int c = (k - 104) >> 1;
            w = f32_to_f16u(W_ih[n * 4 + c] * sc);
        } else if (k < 120) {
            if (!(k & 1)) {                       // k=112+2c: x_hi * W_lo
                int c = (k - 112) >> 1;
                float wf = W_ih[n * 4 + c] * sc;
                unsigned short hi = f32_to_f16u(wf);
                w = f32_to_f16u(wf - f16u_to_f32(hi));
            }
        } else if (k == 120) {                    // b_hi (scaled), A = 1.0
            float bb = (b_ih[n] + b_hh[n]) * sc;
            w = f32_to_f16u(bb);
        } else if (k == 122) {                    // b_lo (scaled), A = 1.0
            float bb = (b_ih[n] + b_hh[n]) * sc;
            unsigned short hi = f32_to_f16u(bb);
            w = f32_to_f16u(bb - f16u_to_f32(hi));
        }
        v[j] = w;
    }
    Bpack[t] = v;
}

// ---------------------------------------------------------------------------
// Main: one block = 16 sequences, full T loop. 4 waves; wave w owns tiles
// {w, w+4, ..., w+20}, wave0 additionally tile 24. Lane cell: unit
// j = tile*4 + quad, seq s = lane&15, acc = {i,f,g,o} in the exp2 domain.
// ALL W in regs (wfrag[7][4]). One barrier per step. LDS = 8,704 B.
// ---------------------------------------------------------------------------
__global__ void __launch_bounds__(256, 2)
lstm_main(const float* __restrict__ x, const ushortx8* __restrict__ Bpack,
          float* __restrict__ out) {
    __shared__ __align__(16) unsigned short s_A[2][16 * KSTR];   // ping-pong, 8,704 B

    const int tid  = threadIdx.x;
    const int lane = tid & 63;
    const int wavu = __builtin_amdgcn_readfirstlane(tid >> 6);   // wave id in SGPR
    const int seq0 = blockIdx.x * S_BLK;
    const int m    = lane & 15;
    const int quad = lane >> 4;
    const int q2   = quad << 1;

    // ---- W fragments: ALL kc in regs (112 regs/wave). wave0 it=6 -> tile 24.
    halfx8 wfrag[7][4];
#pragma unroll
    for (int it = 0; it < 7; ++it) {
        int tile = wavu + it * 4;
        if (tile < NTILE) {
#pragma unroll
            for (int kc = 0; kc < 4; ++kc)
                wfrag[it][kc] = __builtin_bit_cast(halfx8, Bpack[(tile * 4 + kc) * 64 + lane]);
        }
    }

    // h write-col base per owned tile (wave-uniform -> SGPR arithmetic)
    int wb[7];
#pragma unroll
    for (int it = 0; it < 7; ++it) {
        int tile = wavu + it * 4;
        wb[it] = (tile < 24) ? (((tile >> 1) << 3) + (tile & 1)) : 96;
    }

    // refresh-thread x pointer (valid for tid >= 128): (s = rt&15, cc = rt>>4)
    const int rt = tid - 128;
    const int rs = rt & 15, rc = (rt >> 4) & 7;
    const float* xb = x + (size_t)(seq0 + rs) * (T_STEPS * 4) + (rc & 3);

    // ---- zero both buffers (h(0)=0; unused k columns stay 0 forever)
    for (int i = tid; i < (2 * 16 * KSTR) / 2; i += 256)
        ((unsigned int*)s_A)[i] = 0u;
    float x0 = 0.0f;
    if (tid >= 128) x0 = xb[0];
    __syncthreads();
    // ---- x(t=0) into buf0; constant bias-select cols into BOTH buffers
    if (tid >= 128) {
        unsigned short hi = f32_to_f16u(x0);
        if (rc < 4) {
            s_A[0][rs * KSTR + 104 + 2 * rc] = hi;                        // x_hi (W_hi)
            s_A[0][rs * KSTR + 112 + 2 * rc] = hi;                        // x_hi (W_lo)
        } else {
            s_A[0][rs * KSTR + 105 + 2 * (rc - 4)] =
                f32_to_f16u(x0 - f16u_to_f32(hi));                        // x_lo (W_hi)
        }
    } else if (tid < 32) {
        s_A[tid >> 4][(tid & 15) * KSTR + 120] = 0x3C00;   // k120 = 1.0, both bufs
    } else if (tid < 64) {
        int d = tid - 32;
        s_A[d >> 4][(d & 15) * KSTR + 122] = 0x3C00;       // k122 = 1.0, both bufs
    }
    __syncthreads();   // init writes visible before first read

    float c_reg[7];   // cell state in 2*log2e domain (c_reg[6]: wave0 only)
#pragma unroll
    for (int it = 0; it < 7; ++it) c_reg[it] = 0.0f;

    const int rowOff = m * KSTR;
    const int aOff   = rowOff + quad * 8;

    for (int t = 0; t < T_STEPS; ++t) {
        const int bR = t & 1;
        const unsigned short* base  = s_A[bR];
        unsigned short*       baseW = s_A[bR ^ 1];

        // prefetch x(t+1) — issued before compute phase to hide latency
        float xnext = 0.0f;
        if (tid >= 128) {
            int tn = t + 1; if (tn > T_STEPS - 1) tn = T_STEPS - 1;
            xnext = xb[tn * 4];
        }

        // ---- batched LDS reads: the only LDS reads this step (4 x b128)
        halfx8 hh[4];
#pragma unroll
        for (int kc = 0; kc < 4; ++kc)
            hh[kc] = *(const halfx8*)(base + aOff + kc * 32);   // ds_read_b128

        const bool last = (t == T_STEPS - 1);

        auto gemm4 = [&](const halfx8* w) {
            floatx4 a = {0.0f, 0.0f, 0.0f, 0.0f};
            a = __builtin_amdgcn_mfma_f32_16x16x32_f16(w[0], hh[0], a, 0, 0, 0);
            a = __builtin_amdgcn_mfma_f32_16x16x32_f16(w[1], hh[1], a, 0, 0, 0);
            a = __builtin_amdgcn_mfma_f32_16x16x32_f16(w[2], hh[2], a, 0, 0, 0);
            a = __builtin_amdgcn_mfma_f32_16x16x32_f16(w[3], hh[3], a, 0, 0, 0);
            return a;
        };
        auto activate = [&](floatx4 acc, float& cm, int wbase, int jb) {
            // lane = (seq s=m, unit jb+quad); acc = {i,f,g,o}, exp2 domain
            float ei = fexp2(acc[0]);            // e^i
            float ef = fexp2(acc[1]);            // e^f
            float eg = fexp2(acc[2]);            // e^{2g}
            float eo = fexp2(acc[3]);            // e^o
            float a  = 1.0f + ei, b = 1.0f + ef;
            float d  = eg + 1.0f;
            float e2s = fmaf(eg, TWO_L, -TWO_L); // (e^{2g}-1)*2log2e
            float q  = a * d;
            float r  = __builtin_amdgcn_rcpf(q * b);
            float nm = fmaf(ef * q, cm, (ei * b) * e2s);
            float c2 = nm * r;
            cm = c2;
            float cc = fminf(c2, 115.0f);        // exp2 overflow guard
            float ec = fexp2(cc);                // e^{2c}
            float r2 = __builtin_amdgcn_rcpf((1.0f + eo) * (ec + 1.0f));
            float h  = (eo * (ec - 1.0f)) * r2;
            if (!last) {
                baseW[rowOff + wbase + q2] = f32_to_f16u(h);   // permuted col
            } else {
                out[(size_t)(seq0 + m) * H_UNITS + jb + quad] = h;
            }
        };

        // ---- phase 1: all MFMA chains (independent; saturate matrix pipe)
        floatx4 acc[6];
#pragma unroll
        for (int it = 0; it < 6; ++it)
            acc[it] = gemm4(wfrag[it]);
        floatx4 acc24;
        if (wavu == 0) acc24 = gemm4(wfrag[6]);

        // ---- phase 2: all activation chains (6-7 way ILP on VALU/trans)
#pragma unroll
        for (int it = 0; it < 6; ++it)
            activate(acc[it], c_reg[it], wb[it], (wavu + it * 4) * 4);
        if (wavu == 0) activate(acc24, c_reg[6], wb[6], 96);

        if (tid >= 128 && !last) {               // x(t+1) -> other buffer
            unsigned short hi = f32_to_f16u(xnext);
            if (rc < 4) {
                baseW[rs * KSTR + 104 + 2 * rc] = hi;
                baseW[rs * KSTR + 112 + 2 * rc] = hi;
            } else {
                baseW[rs * KSTR + 105 + 2 * (rc - 4)] =
                    f32_to_f16u(xnext - f16u_to_f32(hi));
            }
        }
        __syncthreads();   // single barrier/step: covers both cross-step hazards
    }
}

extern "C" void kernel_launch(void* const* d_in, const int* in_sizes, int n_in,
                              void* d_out, int out_size, void* d_ws, size_t ws_size,
                              hipStream_t stream) {
    const float* x    = (const float*)d_in[0];   // [4096,3,128,4]
    const float* W_ih = (const float*)d_in[1];   // [400,4]
    const float* W_hh = (const float*)d_in[2];   // [400,100]
    const float* b_ih = (const float*)d_in[3];   // [400]
    const float* b_hh = (const float*)d_in[4];   // [400]
    ushortx8* Bpack = (ushortx8*)d_ws;           // 25*4*64*16 B = 102,400 B

    lstm_prep_pack<<<25, 256, 0, stream>>>(W_ih, W_hh, b_ih, b_hh, Bpack);
    lstm_main<<<NBLK, 256, 0, stream>>>(x, Bpack, (float*)d_out);
}

// Round 4
// 283.501 us; speedup vs baseline: 1.0657x; 1.0428x over previous
//
#include <hip/hip_runtime.h>
#include <cstdint>

// ShortTermLSTM on MI355X: batched LSTM, transposed-GEMM f16 MFMA, cell fully
// in registers, fused-rcp activations in the exp2 domain (raw v_exp_f32).
// R15 251 steady (best): 768x4-wave blocks, single barrier, s_W kc0 in LDS.
// R16 269 / R17 262 falsified topology+schedule levers; SQ_LDS_BANK_CONFLICT
// invariant (1.176e7) across LDS-read-count 41->16 => dead diagnostic.
// Cost model: VALU pipe dominant (~140 issue-cyc/docell, ~2x the core math);
// must CUT VALU ops/cell. gfx950 has full-rate V_PK_*_F32 (packed f32).
// R18 (this): PAIR-TILE gate layout + packed float2 activation:
//   tiles <24 come in pairs: tileA rows = {i(u0),i(u1),f(u0),f(u1)} x 4 quads,
//   tileB = {g(u0),g(u1),o(u0),o(u1)}, u0 = 8*pair + 2*quad, u1 = u0+1.
//   Lane acc: accA=(i0,i1,f0,f1), accB=(g0,g1,o0,o1) -> whole activation is
//   2-cell float2 chains -> v_pk_fma/add/mul_f32 (~-35% regular VALU).
//   h-writes: adjacent units -> one ds_write_b32 per pair (was 2x b16).
//   k-map becomes IDENTITY: k=u for h (0..99); x/bias cols as R14:
//     k100..103: x_hi (W hi) ; k104..107: x_lo (W hi) ; k108..111: x_hi (W lo)
//     k112/113: bias hi/lo (A=1.0) ; k114..127: 0.
//   Tile 24 (units 96..99): old scalar path on wave0.
// Residual error: dropped h*W_hh_lo (~6e-5/step); measured margin ~4x.

#define H_UNITS 100
#define T_STEPS 128
#define S_BLK   16
#define NSEQ    12288
#define NBLK    (NSEQ / S_BLK)   // 768
#define NTILE   25               // 100 units / 4 rows-of-4 per tile
#define KSTR    136              // LDS h row stride (ushorts)
#define LOG2E   1.4426950408889634f
#define TWO_L   2.8853900817779268f   // 2*log2(e)

typedef __attribute__((ext_vector_type(8))) _Float16 halfx8;
typedef __attribute__((ext_vector_type(8))) unsigned short ushortx8;
typedef __attribute__((ext_vector_type(4))) float floatx4;
typedef __attribute__((ext_vector_type(2))) float floatx2;

__device__ __forceinline__ unsigned short f32_to_f16u(float x) {
    _Float16 h = (_Float16)x;                       // v_cvt_f16_f32 (RNE)
    return __builtin_bit_cast(unsigned short, h);
}
__device__ __forceinline__ float f16u_to_f32(unsigned short u) {
    _Float16 h = __builtin_bit_cast(_Float16, u);
    return (float)h;
}
#if __has_builtin(__builtin_amdgcn_exp2f)
__device__ __forceinline__ float fexp2(float x) { return __builtin_amdgcn_exp2f(x); }
#else
__device__ __forceinline__ float fexp2(float x) { return exp2f(x); }
#endif

// ---------------------------------------------------------------------------
// Prep: pack W (pre-scaled into exp2 domain) into MFMA A-operand fragments.
// Pair-tile row map (tile<24): pr=tile>>1, half=tile&1, reg=m&3, qr=m>>2:
//   gate = (reg>>1) + 2*half   (A: i,f ; B: g,o)
//   unit = 8*pr + 2*qr + (reg&1)
//   n = gate*100 + unit        (torch gate order i,f,g,o)
// Tile 24: n = (m&3)*100 + 96 + (m>>2)  (old i,f,g,o-per-quad layout).
// k-map: identity for h (k<100), x/bias cols per header.
// ---------------------------------------------------------------------------
__global__ void lstm_prep_pack(const float* __restrict__ W_ih,
                               const float* __restrict__ W_hh,
                               const float* __restrict__ b_ih,
                               const float* __restrict__ b_hh,
                               ushortx8* __restrict__ Bpack) {
    int t = blockIdx.x * 256 + threadIdx.x;   // (tile,kc,lane): 25*4*64 = 6400
    if (t >= NTILE * 4 * 64) return;
    int lane = t & 63;
    int kc   = (t >> 6) & 3;
    int tile = t >> 8;
    int m    = lane & 15;
    int n;
    if (tile < 24) {
        int pr = tile >> 1, half = tile & 1;
        int reg = m & 3,   qr   = m >> 2;
        int g = (reg >> 1) + 2 * half;
        int u = 8 * pr + 2 * qr + (reg & 1);
        n = g * 100 + u;
    } else {
        n = (m & 3) * 100 + 96 + (m >> 2);
    }
    float sc = (n >= 200 && n < 300) ? (2.0f * LOG2E) : LOG2E;   // g rows get 2x
    int k0 = kc * 32 + ((lane >> 4) & 3) * 8;
    ushortx8 v;
#pragma unroll
    for (int j = 0; j < 8; ++j) {
        int k = k0 + j;
        unsigned short w = 0;
        if (k < 100) {
            w = f32_to_f16u(W_hh[n * 100 + k] * sc);             // identity k-map
        } else if (k < 108) {
            w = f32_to_f16u(W_ih[n * 4 + ((k - 100) & 3)] * sc); // hi W (x_hi & x_lo)
        } else if (k < 112) {
            float wf = W_ih[n * 4 + (k - 108)] * sc;             // lo W (x_hi)
            unsigned short hi = f32_to_f16u(wf);
            w = f32_to_f16u(wf - f16u_to_f32(hi));
        } else if (k == 112) {
            float bb = (b_ih[n] + b_hh[n]) * sc;                 // b_hi (A=1.0)
            w = f32_to_f16u(bb);
        } else if (k == 113) {
            float bb = (b_ih[n] + b_hh[n]) * sc;                 // b_lo (A=1.0)
            unsigned short hi = f32_to_f16u(bb);
            w = f32_to_f16u(bb - f16u_to_f32(hi));
        }
        v[j] = w;
    }
    Bpack[t] = v;
}

// ---------------------------------------------------------------------------
// Main: one block = 16 sequences, full T loop. 4 waves; wave w owns pairs
// {w, w+4, w+8} (tiles 2p,2p+1), wave0 additionally tile 24.
// W kc1..3 in regs (wfrag[7][3]); kc0 in s_W (LDS). One barrier per step.
// ---------------------------------------------------------------------------
__global__ void __launch_bounds__(256, 3)
lstm_main(const float* __restrict__ x, const ushortx8* __restrict__ Bpack,
          float* __restrict__ out) {
    __shared__ __align__(16) unsigned short s_A[2][16 * KSTR];   // ping-pong, 2 x 4352 B
    __shared__ __align__(16) ushortx8       s_W[NTILE * 64];     // 25600 B, kc0 frags

    const int tid  = threadIdx.x;
    const int lane = tid & 63;
    const int wavu = __builtin_amdgcn_readfirstlane(tid >> 6);   // wave id in SGPR
    const int seq0 = blockIdx.x * S_BLK;
    const int m    = lane & 15;
    const int quad = lane >> 4;
    const int q2   = quad << 1;

    // ---- W fragments kc1..3 in regs: slots 0..5 = paired tiles, 6 = tile 24
    halfx8 wfrag[7][3];
#pragma unroll
    for (int s = 0; s < 6; ++s) {
        int tile = 2 * (wavu + (s >> 1) * 4) + (s & 1);
#pragma unroll
        for (int kc = 0; kc < 3; ++kc)
            wfrag[s][kc] = __builtin_bit_cast(halfx8, Bpack[(tile * 4 + kc + 1) * 64 + lane]);
    }
    if (wavu == 0) {
#pragma unroll
        for (int kc = 0; kc < 3; ++kc)
            wfrag[6][kc] = __builtin_bit_cast(halfx8, Bpack[(24 * 4 + kc + 1) * 64 + lane]);
    }
    // ---- kc0 frags (all tiles): global -> LDS, once
    for (int i = tid; i < NTILE * 64; i += 256)
        s_W[i] = Bpack[(i >> 6) * 256 + (i & 63)];

    // refresh-thread x pointer (valid for tid >= 128): (s = rt&15, cc = rt>>4)
    const int rt = tid - 128;
    const int rs = rt & 15, rc = (rt >> 4) & 7;
    const float* xb = x + (size_t)(seq0 + rs) * (T_STEPS * 4) + (rc & 3);

    // ---- zero both buffers (h(0)=0; k114..127 stay 0 forever)
    for (int i = tid; i < (2 * 16 * KSTR) / 2; i += 256)
        ((unsigned int*)s_A)[i] = 0u;
    float x0 = 0.0f;
    if (tid >= 128) x0 = xb[0];
    __syncthreads();
    // ---- x(t=0) into buf0; constant bias-select cols into BOTH buffers
    if (tid >= 128) {
        unsigned short hi = f32_to_f16u(x0);
        if (rc < 4) {
            s_A[0][rs * KSTR + 100 + rc] = hi;                    // x_hi (W_hi)
            s_A[0][rs * KSTR + 108 + rc] = hi;                    // x_hi (W_lo)
        } else {
            s_A[0][rs * KSTR + 104 + (rc - 4)] =
                f32_to_f16u(x0 - f16u_to_f32(hi));                // x_lo (W_hi)
        }
    } else if (tid < 32) {
        s_A[tid >> 4][(tid & 15) * KSTR + 112] = 0x3C00;   // k112 = 1.0, both bufs
    } else if (tid < 64) {
        int d = tid - 32;
        s_A[d >> 4][(d & 15) * KSTR + 113] = 0x3C00;       // k113 = 1.0, both bufs
    }
    __syncthreads();   // init writes visible before first read

    floatx2 cpr[3];   // cell state pairs (u0,u1) per owned pair, 2*log2e domain
#pragma unroll
    for (int it = 0; it < 3; ++it) cpr[it] = (floatx2){0.0f, 0.0f};
    float c24 = 0.0f;

    const int rowOff = m * KSTR;
    const int aOff   = rowOff + quad * 8;

    for (int t = 0; t < T_STEPS; ++t) {
        const int bR = t & 1;
        const unsigned short* base  = s_A[bR];
        unsigned short*       baseW = s_A[bR ^ 1];

        // prefetch x(t+1) — issued before compute phase to hide latency
        float xnext = 0.0f;
        if (tid >= 128) {
            int tn = t + 1; if (tn > T_STEPS - 1) tn = T_STEPS - 1;
            xnext = xb[tn * 4];
        }

        halfx8 hh[4];
#pragma unroll
        for (int kc = 0; kc < 4; ++kc)
            hh[kc] = *(const halfx8*)(base + aOff + kc * 32);   // ds_read_b128

        const bool last = (t == T_STEPS - 1);

        auto gemm4 = [&](halfx8 w0, const halfx8* w123) {
            floatx4 a = {0.0f, 0.0f, 0.0f, 0.0f};
            a = __builtin_amdgcn_mfma_f32_16x16x32_f16(w0,      hh[0], a, 0, 0, 0);
            a = __builtin_amdgcn_mfma_f32_16x16x32_f16(w123[0], hh[1], a, 0, 0, 0);
            a = __builtin_amdgcn_mfma_f32_16x16x32_f16(w123[1], hh[2], a, 0, 0, 0);
            a = __builtin_amdgcn_mfma_f32_16x16x32_f16(w123[2], hh[3], a, 0, 0, 0);
            return a;
        };

        // packed 2-cell activation: accA=(i0,i1,f0,f1), accB=(g0,g1,o0,o1)
        auto activatePair = [&](floatx4 aA, floatx4 aB, floatx2& cm, int p) {
            floatx2 ei = {fexp2(aA[0]), fexp2(aA[1])};   // e^i
            floatx2 ef = {fexp2(aA[2]), fexp2(aA[3])};   // e^f
            floatx2 eg = {fexp2(aB[0]), fexp2(aB[1])};   // e^{2g}
            floatx2 eo = {fexp2(aB[2]), fexp2(aB[3])};   // e^o
            floatx2 a  = ei + 1.0f;                      // v_pk_add_f32
            floatx2 b  = ef + 1.0f;
            floatx2 d  = eg + 1.0f;
            floatx2 p1 = eo + 1.0f;
            floatx2 e2s = eg * TWO_L - TWO_L;            // v_pk_fma_f32
            floatx2 q  = a * d;
            floatx2 qb = q * b;
            floatx2 r  = {__builtin_amdgcn_rcpf(qb[0]), __builtin_amdgcn_rcpf(qb[1])};
            floatx2 eib = ei * b;
            floatx2 efq = ef * q;
            floatx2 tt  = eib * e2s;
            floatx2 nm  = efq * cm + tt;                 // v_pk_fma_f32
            floatx2 c2  = nm * r;
            cm = c2;
            floatx2 cc = {fminf(c2[0], 115.0f), fminf(c2[1], 115.0f)};
            floatx2 ec = {fexp2(cc[0]), fexp2(cc[1])};   // e^{2c}
            floatx2 p2 = ec + 1.0f;
            floatx2 nu = ec - 1.0f;
            floatx2 pp = p1 * p2;
            floatx2 r2 = {__builtin_amdgcn_rcpf(pp[0]), __builtin_amdgcn_rcpf(pp[1])};
            floatx2 eon = eo * nu;
            floatx2 hv  = eon * r2;
            if (!last) {
                unsigned int pk = (unsigned int)f32_to_f16u(hv[0]) |
                                  ((unsigned int)f32_to_f16u(hv[1]) << 16);
                *(unsigned int*)&baseW[rowOff + 8 * p + q2] = pk;   // ds_write_b32
            } else {
                *(floatx2*)&out[(size_t)(seq0 + m) * H_UNITS + 8 * p + q2] = hv;
            }
        };

#pragma unroll
        for (int it = 0; it < 3; ++it) {                 // 3 pairs per wave
            int p = wavu + it * 4;
            halfx8 w0A = __builtin_bit_cast(halfx8, s_W[(2 * p) * 64 + lane]);
            halfx8 w0B = __builtin_bit_cast(halfx8, s_W[(2 * p + 1) * 64 + lane]);
            floatx4 aA = gemm4(w0A, wfrag[2 * it]);
            floatx4 aB = gemm4(w0B, wfrag[2 * it + 1]);
            activatePair(aA, aB, cpr[it], p);
        }

        if (wavu == 0) {   // tile 24 (units 96..99): scalar path
            halfx8 w0 = __builtin_bit_cast(halfx8, s_W[24 * 64 + lane]);
            floatx4 acc = gemm4(w0, wfrag[6]);
            float ei = fexp2(acc[0]);
            float ef = fexp2(acc[1]);
            float eg = fexp2(acc[2]);
            float eo = fexp2(acc[3]);
            float a  = 1.0f + ei, b = 1.0f + ef;
            float d  = eg + 1.0f;
            float e2s = fmaf(eg, TWO_L, -TWO_L);
            float q  = a * d;
            float r  = __builtin_amdgcn_rcpf(q * b);
            float nm = fmaf(ef * q, c24, (ei * b) * e2s);
            float c2 = nm * r;
            c24 = c2;
            float cc = fminf(c2, 115.0f);
            float ec = fexp2(cc);
            float r2 = __builtin_amdgcn_rcpf((1.0f + eo) * (ec + 1.0f));
            float h  = (eo * (ec - 1.0f)) * r2;
            if (!last) {
                baseW[rowOff + 96 + quad] = f32_to_f16u(h);        // k = unit
            } else {
                out[(size_t)(seq0 + m) * H_UNITS + 96 + quad] = h;
            }
        }

        if (tid >= 128 && !last) {               // x(t+1) -> other buffer
            unsigned short hi = f32_to_f16u(xnext);
            if (rc < 4) {
                baseW[rs * KSTR + 100 + rc] = hi;
                baseW[rs * KSTR + 108 + rc] = hi;
            } else {
                baseW[rs * KSTR + 104 + (rc - 4)] =
                    f32_to_f16u(xnext - f16u_to_f32(hi));
            }
        }
        __syncthreads();   // single barrier/step: covers both cross-step hazards
    }
}

extern "C" void kernel_launch(void* const* d_in, const int* in_sizes, int n_in,
                              void* d_out, int out_size, void* d_ws, size_t ws_size,
                              hipStream_t stream) {
    const float* x    = (const float*)d_in[0];   // [4096,3,128,4]
    const float* W_ih = (const float*)d_in[1];   // [400,4]
    const float* W_hh = (const float*)d_in[2];   // [400,100]
    const float* b_ih = (const float*)d_in[3];   // [400]
    const float* b_hh = (const float*)d_in[4];   // [400]
    ushortx8* Bpack = (ushortx8*)d_ws;           // 25*4*64*16 B = 102,400 B

    lstm_prep_pack<<<25, 256, 0, stream>>>(W_ih, W_hh, b_ih, b_hh, Bpack);
    lstm_main<<<NBLK, 256, 0, stream>>>(x, Bpack, (float*)d_out);
}